// Round 3
// baseline (251.820 us; speedup 1.0000x reference)
//
#include <hip/hip_runtime.h>
#include <hip/hip_bf16.h>
#include <stdint.h>

typedef __attribute__((ext_vector_type(8))) short bf16x8;
typedef __attribute__((ext_vector_type(4))) short bf16x4;
typedef __attribute__((ext_vector_type(4))) float f32x4;
typedef __attribute__((ext_vector_type(4))) unsigned u32x4;

#define L2E 1.4426950408889634f

static __device__ __forceinline__ unsigned short f2bf(float f) {
    __hip_bfloat16 h = __float2bfloat16(f);
    return __builtin_bit_cast(unsigned short, h);
}

static __device__ __forceinline__ void gl2lds16(const void* g, void* l) {
    __builtin_amdgcn_global_load_lds(
        (const __attribute__((address_space(1))) void*)g,
        (__attribute__((address_space(3))) void*)l,
        16, 0, 0);
}

// ---------------- cast fp32 -> bf16 ----------------
__global__ void cast_kernel(const float* __restrict__ src,
                            unsigned short* __restrict__ dst, int n4) {
    int i = blockIdx.x * blockDim.x + threadIdx.x;
    int stride = gridDim.x * blockDim.x;
    for (; i < n4; i += stride) {
        float4 v = ((const float4*)src)[i];
        ushort4 o;
        o.x = f2bf(v.x); o.y = f2bf(v.y); o.z = f2bf(v.z); o.w = f2bf(v.w);
        ((ushort4*)dst)[i] = o;
    }
}

// ---------------- GEMM: C[i][j] = sum_k A[i][k] * W[j][k]  (torch Linear) ----
// OM: 0 = bf16 row-major, 1 = f32 row-major, 2 = bf16 transposed V^T [bh][d][s]
template<int OM>
__global__ __launch_bounds__(256) void gemm_bt(
    const unsigned short* __restrict__ A,
    const unsigned short* __restrict__ W,
    const float* __restrict__ bias,
    const float* __restrict__ bias2,
    float scale,
    unsigned short* __restrict__ obf,
    float* __restrict__ of)
{
    constexpr int K = 1024;
    __shared__ unsigned short As[128][64];
    __shared__ unsigned short Bs[128][64];

    const int tid  = threadIdx.x;
    const int wave = tid >> 6, lane = tid & 63;
    const int li = lane & 15, lg = lane >> 4;
    const int m0 = blockIdx.y * 128, n0 = blockIdx.x * 128;
    const int wm = (wave >> 1) * 64, wn = (wave & 1) * 64;

    const int srow = wave * 8 + (lane >> 3);
    const int scol = (lane & 7) * 8;

    f32x4 acc[4][4] = {};

    for (int k0 = 0; k0 < K; k0 += 64) {
#pragma unroll
        for (int rnd = 0; rnd < 4; ++rnd)
            gl2lds16(A + (size_t)(m0 + rnd * 32 + srow) * K + k0 + scol,
                     &As[rnd * 32 + wave * 8][0]);
#pragma unroll
        for (int rnd = 0; rnd < 4; ++rnd)
            gl2lds16(W + (size_t)(n0 + rnd * 32 + srow) * K + k0 + scol,
                     &Bs[rnd * 32 + wave * 8][0]);
        __syncthreads();
#pragma unroll
        for (int kk = 0; kk < 64; kk += 32) {
            bf16x8 af[4], bfr[4];
#pragma unroll
            for (int m = 0; m < 4; ++m)
                af[m] = *(const bf16x8*)&As[wm + m * 16 + li][kk + lg * 8];
#pragma unroll
            for (int n = 0; n < 4; ++n)
                bfr[n] = *(const bf16x8*)&Bs[wn + n * 16 + li][kk + lg * 8];
#pragma unroll
            for (int m = 0; m < 4; ++m)
#pragma unroll
                for (int n = 0; n < 4; ++n)
                    acc[m][n] = __builtin_amdgcn_mfma_f32_16x16x32_bf16(
                        af[m], bfr[n], acc[m][n], 0, 0, 0);
        }
        __syncthreads();
    }

#pragma unroll
    for (int n = 0; n < 4; ++n) {
        const int col = n0 + wn + n * 16 + li;
        float bb = bias[col];
        if (bias2) bb += bias2[col];
#pragma unroll
        for (int m = 0; m < 4; ++m) {
            if (OM == 2) {
                const int row0 = m0 + wm + m * 16 + lg * 4;
                size_t addr = ((size_t)(((row0 >> 11) << 4) + (col >> 6)) * 64 + (col & 63)) * 2048
                              + (row0 & 2047);
                ushort4 o;
                o.x = f2bf((acc[m][n][0] + bb) * scale);
                o.y = f2bf((acc[m][n][1] + bb) * scale);
                o.z = f2bf((acc[m][n][2] + bb) * scale);
                o.w = f2bf((acc[m][n][3] + bb) * scale);
                *(ushort4*)&obf[addr] = o;
            } else {
#pragma unroll
                for (int r = 0; r < 4; ++r) {
                    const int row = m0 + wm + m * 16 + lg * 4 + r;
                    float v = (acc[m][n][r] + bb) * scale;
                    if (OM == 1) of[(size_t)row * 1024 + col] = v;
                    else         obf[(size_t)row * 1024 + col] = f2bf(v);
                }
            }
        }
    }
}

// ---------------- fused flash attention ----------------
// Q pre-scaled by (1/8)*log2(e). No max-subtraction (scores bounded; softmax
// is shift-invariant). 4 waves x 2 q-sets x 16 rows = 128 q-rows per block.
// K and V^T staged via global_load_lds with XOR-swizzled global source.
// P never touches LDS: in-register redistribution via permlane32_swap +
// ds_swizzle xor16 butterfly (value (lane a,b; word c,d,p) -> (lane d,a; word c,b,p)).
__global__ __launch_bounds__(256, 4) void attn_kernel(
    const unsigned short* __restrict__ Q,
    const unsigned short* __restrict__ Km,
    const unsigned short* __restrict__ VT,
    unsigned short* __restrict__ AO)
{
    __shared__ unsigned short Ks[2][4096];      // [buf][64 j][64 d] swizzled
    __shared__ unsigned short Vs[2][4096];      // [buf][64 d][64 j] swizzled

    const int tid  = threadIdx.x;
    const int w = tid >> 6, lane = tid & 63;
    const int li = lane & 15, lg = lane >> 4, li7 = li & 7;

    // XCD-chunked swizzle over 1024 blocks (16 x 64 grid)
    const int p  = blockIdx.y * 16 + blockIdx.x;
    const int q_ = (p & 7) * 128 + (p >> 3);
    const int bx = q_ & 15, bh = q_ >> 4;
    const int b = bh >> 4, h = bh & 15;
    const int q0 = bx * 128;
    const int qb0 = q0 + w * 32;                // set0 base; set1 = +16

    const int srow = w * 16 + (lane >> 3);
    const int swz  = ((lane & 7) ^ (lane >> 3)) * 8;

    const unsigned short* Kg0 = Km + (size_t)(b * 2048 + srow) * 1024 + h * 64 + swz;
    const unsigned short* Vg0 = VT + ((size_t)bh * 64 + srow) * 2048 + swz;

    bf16x8 qf[2][2];
#pragma unroll
    for (int s = 0; s < 2; ++s)
#pragma unroll
        for (int t = 0; t < 2; ++t)
            qf[s][t] = *(const bf16x8*)&Q[(size_t)(b * 2048 + qb0 + s * 16 + li) * 1024
                                          + h * 64 + t * 32 + lg * 8];

    f32x4 acc[2][4] = {};
    float lr[2] = {0.f, 0.f};

#pragma unroll
    for (int it = 0; it < 2; ++it) {
        gl2lds16(Kg0 + (size_t)(it * 8) * 1024, &Ks[0][(w * 2 + it) * 512]);
        gl2lds16(Vg0 + (size_t)(it * 8) * 2048, &Vs[0][(w * 2 + it) * 512]);
    }
    __syncthreads();

    for (int t = 0; t < 32; ++t) {
        const int buf = t & 1;
        const int j0 = t * 64;
        if (t < 31) {
            const int j1 = j0 + 64;
#pragma unroll
            for (int it = 0; it < 2; ++it) {
                gl2lds16(Kg0 + (size_t)(j1 + it * 8) * 1024, &Ks[buf ^ 1][(w * 2 + it) * 512]);
                gl2lds16(Vg0 + (size_t)(it * 8) * 2048 + j1, &Vs[buf ^ 1][(w * 2 + it) * 512]);
            }
        }

        // K fragments (shared across both q-sets)
        bf16x8 kf[2][4];
#pragma unroll
        for (int tt = 0; tt < 2; ++tt)
#pragma unroll
            for (int jf = 0; jf < 4; ++jf)
                kf[tt][jf] = *(const bf16x8*)&Ks[buf][(jf * 16 + li) * 64
                                                      + ((tt * 4 + lg) ^ li7) * 8];

        unsigned pw[2][8];
#pragma unroll
        for (int s = 0; s < 2; ++s) {
            f32x4 st[4];
            __builtin_amdgcn_s_setprio(1);
#pragma unroll
            for (int jf = 0; jf < 4; ++jf) {
                f32x4 z = {};
                z = __builtin_amdgcn_mfma_f32_16x16x32_bf16(kf[0][jf], qf[s][0], z, 0, 0, 0);
                st[jf] = __builtin_amdgcn_mfma_f32_16x16x32_bf16(kf[1][jf], qf[s][1], z, 0, 0, 0);
            }
            __builtin_amdgcn_s_setprio(0);
            const int qb = qb0 + s * 16;
            if (j0 + 65 >= qb && j0 <= qb + 17) {
#pragma unroll
                for (int jf = 0; jf < 4; ++jf)
#pragma unroll
                    for (int r = 0; r < 4; ++r) {
                        int dq = (qb + li) - (j0 + jf * 16 + lg * 4 + r);
                        if ((unsigned)(dq + 2) <= 4u) st[jf][r] += 0.1f * L2E;
                    }
            }
            float ps = 0.f;
#pragma unroll
            for (int jf = 0; jf < 4; ++jf) {
                float p0 = __builtin_amdgcn_exp2f(st[jf][0]);
                float p1 = __builtin_amdgcn_exp2f(st[jf][1]);
                float p2 = __builtin_amdgcn_exp2f(st[jf][2]);
                float p3 = __builtin_amdgcn_exp2f(st[jf][3]);
                ps += (p0 + p1) + (p2 + p3);
                pw[s][jf * 2 + 0] = (unsigned)f2bf(p0) | ((unsigned)f2bf(p1) << 16);
                pw[s][jf * 2 + 1] = (unsigned)f2bf(p2) | ((unsigned)f2bf(p3) << 16);
            }
            lr[s] += ps;

            // stage A: permlane32_swap exchanges word-bit d with lane-bit a
            // pairs (4c+p, 4c+2+p): (0,2) (1,3) (4,6) (5,7)
#pragma unroll
            for (int c = 0; c < 2; ++c)
#pragma unroll
                for (int pp = 0; pp < 2; ++pp) {
                    unsigned a0 = pw[s][c * 4 + pp];
                    unsigned b0 = pw[s][c * 4 + 2 + pp];
                    asm volatile("v_permlane32_swap_b32 %0, %1"
                                 : "+v"(a0), "+v"(b0));
                    pw[s][c * 4 + pp] = a0;
                    pw[s][c * 4 + 2 + pp] = b0;
                }
            // stage B: xor16 butterfly exchanges lane-bit b with word bit1
            const bool bhi = (lane & 16) != 0;
#pragma unroll
            for (int c = 0; c < 2; ++c)
#pragma unroll
                for (int pp = 0; pp < 2; ++pp) {
                    unsigned s0 = pw[s][c * 4 + pp];
                    unsigned s1 = pw[s][c * 4 + 2 + pp];
                    unsigned sel = bhi ? s0 : s1;
                    unsigned got = (unsigned)__builtin_amdgcn_ds_swizzle((int)sel, 0x401F);
                    pw[s][c * 4 + pp]     = bhi ? got : s0;
                    pw[s][c * 4 + 2 + pp] = bhi ? s1 : got;
                }
        }

        // V fragments (shared across sets) + PV
        bf16x8 vf[2][4];
#pragma unroll
        for (int tt = 0; tt < 2; ++tt)
#pragma unroll
            for (int db = 0; db < 4; ++db)
                vf[tt][db] = *(const bf16x8*)&Vs[buf][(db * 16 + li) * 64
                                                      + ((tt * 4 + lg) ^ li7) * 8];
        __builtin_amdgcn_s_setprio(1);
#pragma unroll
        for (int s = 0; s < 2; ++s) {
            u32x4 t0 = {pw[s][0], pw[s][1], pw[s][2], pw[s][3]};
            u32x4 t1 = {pw[s][4], pw[s][5], pw[s][6], pw[s][7]};
            bf16x8 pf0 = __builtin_bit_cast(bf16x8, t0);
            bf16x8 pf1 = __builtin_bit_cast(bf16x8, t1);
#pragma unroll
            for (int db = 0; db < 4; ++db) {
                acc[s][db] = __builtin_amdgcn_mfma_f32_16x16x32_bf16(vf[0][db], pf0, acc[s][db], 0, 0, 0);
                acc[s][db] = __builtin_amdgcn_mfma_f32_16x16x32_bf16(vf[1][db], pf1, acc[s][db], 0, 0, 0);
            }
        }
        __builtin_amdgcn_s_setprio(0);
        __syncthreads();
    }

#pragma unroll
    for (int s = 0; s < 2; ++s) {
        float l2 = lr[s] + __shfl_xor(lr[s], 16);
        l2 += __shfl_xor(l2, 32);
        const float inv = 1.f / l2;
#pragma unroll
        for (int db = 0; db < 4; ++db) {
            ushort4 o;
            o.x = f2bf(acc[s][db][0] * inv); o.y = f2bf(acc[s][db][1] * inv);
            o.z = f2bf(acc[s][db][2] * inv); o.w = f2bf(acc[s][db][3] * inv);
            *(ushort4*)&AO[(size_t)(b * 2048 + qb0 + s * 16 + li) * 1024
                           + h * 64 + db * 16 + lg * 4] = o;
        }
    }
}

// ---------------- launch ----------------
extern "C" void kernel_launch(void* const* d_in, const int* in_sizes, int n_in,
                              void* d_out, int out_size, void* d_ws, size_t ws_size,
                              hipStream_t stream) {
    const float* x   = (const float*)d_in[0];
    const float* Wq  = (const float*)d_in[2];
    const float* bq  = (const float*)d_in[3];
    const float* Wk  = (const float*)d_in[4];
    const float* bk  = (const float*)d_in[5];
    const float* Wv  = (const float*)d_in[6];
    const float* bv  = (const float*)d_in[7];
    const float* Wo  = (const float*)d_in[8];
    const float* bo  = (const float*)d_in[9];
    const float* ocr = (const float*)d_in[10];
    float* out = (float*)d_out;

    char* ws = (char*)d_ws;
    const size_t MB = 1024 * 1024;
    unsigned short* xb  = (unsigned short*)(ws);            // 16 MB (reused as AO)
    unsigned short* Wqb = (unsigned short*)(ws + 16 * MB);  // 2 MB each
    unsigned short* Wkb = (unsigned short*)(ws + 18 * MB);
    unsigned short* Wvb = (unsigned short*)(ws + 20 * MB);
    unsigned short* Wob = (unsigned short*)(ws + 22 * MB);
    unsigned short* Qb  = (unsigned short*)(ws + 24 * MB);  // 16 MB
    unsigned short* Kb  = (unsigned short*)(ws + 40 * MB);  // 16 MB
    unsigned short* VTb = (unsigned short*)(ws + 56 * MB);  // 16 MB, [bh][d][s]
    unsigned short* AO  = xb;  // x dead after projections

    cast_kernel<<<2048, 256, 0, stream>>>(x,  xb,  8388608 / 4);
    cast_kernel<<<512,  256, 0, stream>>>(Wq, Wqb, 1048576 / 4);
    cast_kernel<<<512,  256, 0, stream>>>(Wk, Wkb, 1048576 / 4);
    cast_kernel<<<512,  256, 0, stream>>>(Wv, Wvb, 1048576 / 4);
    cast_kernel<<<512,  256, 0, stream>>>(Wo, Wob, 1048576 / 4);

    dim3 g(8, 64);
    const float QSC = 0.125f * L2E;  // fold 1/sqrt(64) and log2(e) into Q
    gemm_bt<0><<<g, 256, 0, stream>>>(xb, Wqb, bq, ocr,     QSC, Qb,  nullptr);
    gemm_bt<0><<<g, 256, 0, stream>>>(xb, Wkb, bk, nullptr, 1.f, Kb,  nullptr);
    gemm_bt<2><<<g, 256, 0, stream>>>(xb, Wvb, bv, nullptr, 1.f, VTb, nullptr);

    attn_kernel<<<dim3(16, 64), 256, 0, stream>>>(Qb, Kb, VTb, AO);

    gemm_bt<1><<<g, 256, 0, stream>>>(AO, Wob, bo, nullptr, 1.f, nullptr, out);
}

// Round 4
// 229.811 us; speedup vs baseline: 1.0958x; 1.0958x over previous
//
#include <hip/hip_runtime.h>
#include <hip/hip_bf16.h>
#include <stdint.h>

typedef __attribute__((ext_vector_type(8))) short bf16x8;
typedef __attribute__((ext_vector_type(4))) float f32x4;
typedef __attribute__((ext_vector_type(16))) float f32x16;
typedef __attribute__((ext_vector_type(4))) unsigned u32x4;

#define L2E 1.4426950408889634f

static __device__ __forceinline__ unsigned short f2bf(float f) {
    __hip_bfloat16 h = __float2bfloat16(f);
    return __builtin_bit_cast(unsigned short, h);
}

static __device__ __forceinline__ void gl2lds16(const void* g, void* l) {
    __builtin_amdgcn_global_load_lds(
        (const __attribute__((address_space(1))) void*)g,
        (__attribute__((address_space(3))) void*)l,
        16, 0, 0);
}

// ---------------- cast fp32 -> bf16 ----------------
__global__ void cast_kernel(const float* __restrict__ src,
                            unsigned short* __restrict__ dst, int n4) {
    int i = blockIdx.x * blockDim.x + threadIdx.x;
    int stride = gridDim.x * blockDim.x;
    for (; i < n4; i += stride) {
        float4 v = ((const float4*)src)[i];
        ushort4 o;
        o.x = f2bf(v.x); o.y = f2bf(v.y); o.z = f2bf(v.z); o.w = f2bf(v.w);
        ((ushort4*)dst)[i] = o;
    }
}

// ---------------- GEMM: C[i][j] = sum_k A[i][k] * W[j][k]  (torch Linear) ----
// OM: 0 = bf16 row-major, 1 = f32 row-major, 2 = bf16 transposed V^T [bh][d][s]
// Grid is fixed (8, 64); XCD-chunked bijective remap (512 = 8 x 64).
template<int OM>
__global__ __launch_bounds__(256) void gemm_bt(
    const unsigned short* __restrict__ A,
    const unsigned short* __restrict__ W,
    const float* __restrict__ bias,
    const float* __restrict__ bias2,
    float scale,
    unsigned short* __restrict__ obf,
    float* __restrict__ of)
{
    constexpr int K = 1024;
    __shared__ unsigned short As[128][64];
    __shared__ unsigned short Bs[128][64];

    const int tid  = threadIdx.x;
    const int wave = tid >> 6, lane = tid & 63;
    const int li = lane & 15, lg = lane >> 4;
    const int lin = blockIdx.y * 8 + blockIdx.x;
    const int n2  = (lin & 7) * 64 + (lin >> 3);   // XCD-chunked, bijective
    const int m0 = (n2 >> 3) * 128, n0 = (n2 & 7) * 128;
    const int wm = (wave >> 1) * 64, wn = (wave & 1) * 64;

    const int srow = wave * 8 + (lane >> 3);
    const int scol = (lane & 7) * 8;

    f32x4 acc[4][4] = {};

    for (int k0 = 0; k0 < K; k0 += 64) {
#pragma unroll
        for (int rnd = 0; rnd < 4; ++rnd)
            gl2lds16(A + (size_t)(m0 + rnd * 32 + srow) * K + k0 + scol,
                     &As[rnd * 32 + wave * 8][0]);
#pragma unroll
        for (int rnd = 0; rnd < 4; ++rnd)
            gl2lds16(W + (size_t)(n0 + rnd * 32 + srow) * K + k0 + scol,
                     &Bs[rnd * 32 + wave * 8][0]);
        __syncthreads();
#pragma unroll
        for (int kk = 0; kk < 64; kk += 32) {
            bf16x8 af[4], bfr[4];
#pragma unroll
            for (int m = 0; m < 4; ++m)
                af[m] = *(const bf16x8*)&As[wm + m * 16 + li][kk + lg * 8];
#pragma unroll
            for (int n = 0; n < 4; ++n)
                bfr[n] = *(const bf16x8*)&Bs[wn + n * 16 + li][kk + lg * 8];
#pragma unroll
            for (int m = 0; m < 4; ++m)
#pragma unroll
                for (int n = 0; n < 4; ++n)
                    acc[m][n] = __builtin_amdgcn_mfma_f32_16x16x32_bf16(
                        af[m], bfr[n], acc[m][n], 0, 0, 0);
        }
        __syncthreads();
    }

#pragma unroll
    for (int n = 0; n < 4; ++n) {
        const int col = n0 + wn + n * 16 + li;
        float bb = bias[col];
        if (bias2) bb += bias2[col];
#pragma unroll
        for (int m = 0; m < 4; ++m) {
            if (OM == 2) {
                const int row0 = m0 + wm + m * 16 + lg * 4;
                size_t addr = ((size_t)(((row0 >> 11) << 4) + (col >> 6)) * 64 + (col & 63)) * 2048
                              + (row0 & 2047);
                ushort4 o;
                o.x = f2bf((acc[m][n][0] + bb) * scale);
                o.y = f2bf((acc[m][n][1] + bb) * scale);
                o.z = f2bf((acc[m][n][2] + bb) * scale);
                o.w = f2bf((acc[m][n][3] + bb) * scale);
                *(ushort4*)&obf[addr] = o;
            } else {
#pragma unroll
                for (int r = 0; r < 4; ++r) {
                    const int row = m0 + wm + m * 16 + lg * 4 + r;
                    float v = (acc[m][n][r] + bb) * scale;
                    if (OM == 1) of[(size_t)row * 1024 + col] = v;
                    else         obf[(size_t)row * 1024 + col] = f2bf(v);
                }
            }
        }
    }
}

// ---------------- fused flash attention (32x32x16 MFMA) ----------------
// Q pre-scaled by (1/8)*log2(e). No max-subtraction. 4 waves x 32 q-rows.
// Swapped QK^T with 32x32 MFMA keeps q in lane[4:0]; the P -> PV-B-operand
// permutation is ONE transposition: 8 x v_permlane32_swap_b32 per tile.
__global__ __launch_bounds__(256, 4) void attn_kernel(
    const unsigned short* __restrict__ Q,
    const unsigned short* __restrict__ Km,
    const unsigned short* __restrict__ VT,
    unsigned short* __restrict__ AO)
{
    __shared__ unsigned short Ks[2][4096];      // [buf][64 j][64 d] 16B-chunk XOR-swz
    __shared__ unsigned short Vs[2][4096];      // [buf][64 d][64 j] 16B-chunk XOR-swz

    const int tid  = threadIdx.x;
    const int w = tid >> 6, lane = tid & 63;
    const int li5 = lane & 31, l5 = lane >> 5, li7 = li5 & 7;

    // XCD-chunked swizzle over 1024 blocks (16 x 64 grid)
    const int p  = blockIdx.y * 16 + blockIdx.x;
    const int q_ = (p & 7) * 128 + (p >> 3);
    const int bx = q_ & 15, bh = q_ >> 4;
    const int b = bh >> 4, h = bh & 15;
    const int qb = bx * 128 + w * 32;           // this wave's 32 q-rows
    const int qrow = qb + li5;

    const int srow = w * 16 + (lane >> 3);
    const int swz  = ((lane & 7) ^ (lane >> 3)) * 8;

    const unsigned short* Kg0 = Km + (size_t)(b * 2048 + srow) * 1024 + h * 64 + swz;
    const unsigned short* Vg0 = VT + ((size_t)bh * 64 + srow) * 2048 + swz;

    // Q B-fragments: qf[f] = Q[qrow][d = f*16 + l5*8 + e]
    bf16x8 qf[4];
#pragma unroll
    for (int f = 0; f < 4; ++f)
        qf[f] = *(const bf16x8*)&Q[(size_t)(b * 2048 + qrow) * 1024 + h * 64
                                   + f * 16 + l5 * 8];

    f32x16 acc[2] = {};
    float lr = 0.f;

#pragma unroll
    for (int it = 0; it < 2; ++it) {
        gl2lds16(Kg0 + (size_t)(it * 8) * 1024, &Ks[0][(w * 2 + it) * 512]);
        gl2lds16(Vg0 + (size_t)(it * 8) * 2048, &Vs[0][(w * 2 + it) * 512]);
    }
    __syncthreads();

    for (int t = 0; t < 32; ++t) {
        const int buf = t & 1;
        const int j0 = t * 64;
        if (t < 31) {
            const int j1 = j0 + 64;
#pragma unroll
            for (int it = 0; it < 2; ++it) {
                gl2lds16(Kg0 + (size_t)(j1 + it * 8) * 1024, &Ks[buf ^ 1][(w * 2 + it) * 512]);
                gl2lds16(Vg0 + (size_t)(it * 8) * 2048 + j1, &Vs[buf ^ 1][(w * 2 + it) * 512]);
            }
        }

        // QK^T: st[jf][reg] = S[q=li5][j = j0 + jf*32 + (reg&3) + 8*(reg>>2) + 4*l5]
        f32x16 st[2];
        __builtin_amdgcn_s_setprio(1);
#pragma unroll
        for (int jf = 0; jf < 2; ++jf) {
            f32x16 z = {};
#pragma unroll
            for (int f = 0; f < 4; ++f) {
                bf16x8 kf = *(const bf16x8*)&Ks[buf][(jf * 32 + li5) * 64
                                                     + ((f * 2 + l5) ^ li7) * 8];
                z = __builtin_amdgcn_mfma_f32_32x32x16_bf16(kf, qf[f], z, 0, 0, 0);
            }
            st[jf] = z;
        }
        __builtin_amdgcn_s_setprio(0);

        // band mask (exp2 domain)
        if (j0 >= qb - 65 && j0 <= qb + 33) {
#pragma unroll
            for (int jf = 0; jf < 2; ++jf)
#pragma unroll
                for (int r = 0; r < 16; ++r) {
                    int j = j0 + jf * 32 + (r & 3) + 8 * (r >> 2) + 4 * l5;
                    int dq = qrow - j;
                    if ((unsigned)(dq + 2) <= 4u) st[jf][r] += 0.1f * L2E;
                }
        }

        // exp2 + pack: pw[jf][m] holds P pair (j even, j odd); m[0]=j[1], m[2:1]=j[4:3]
        unsigned pw[2][8];
        float ps = 0.f;
#pragma unroll
        for (int jf = 0; jf < 2; ++jf)
#pragma unroll
            for (int m = 0; m < 8; ++m) {
                float p0 = __builtin_amdgcn_exp2f(st[jf][2 * m]);
                float p1 = __builtin_amdgcn_exp2f(st[jf][2 * m + 1]);
                ps += p0 + p1;
                pw[jf][m] = (unsigned)f2bf(p0) | ((unsigned)f2bf(p1) << 16);
            }
        lr += ps;

        // single-transposition redistribution: swap word-bit m[1] (=j[3]) with
        // lane[5] (=j[2]).  A'={A.lo,B.lo}, B'={A.hi,B.hi}.
#pragma unroll
        for (int jf = 0; jf < 2; ++jf)
#pragma unroll
            for (int m2 = 0; m2 < 2; ++m2)
#pragma unroll
                for (int m0_ = 0; m0_ < 2; ++m0_) {
                    unsigned a0 = pw[jf][m2 * 4 + m0_];
                    unsigned b0 = pw[jf][m2 * 4 + m0_ + 2];
                    asm volatile("v_permlane32_swap_b32 %0, %1"
                                 : "+v"(a0), "+v"(b0));
                    pw[jf][m2 * 4 + m0_]     = a0;
                    pw[jf][m2 * 4 + m0_ + 2] = b0;
                }

        // PV: acc[db] += V^T-frag x P-frag;  frag tt covers j in [tt*16, tt*16+16)
        __builtin_amdgcn_s_setprio(1);
#pragma unroll
        for (int db = 0; db < 2; ++db)
#pragma unroll
            for (int tt = 0; tt < 4; ++tt) {
                bf16x8 vf = *(const bf16x8*)&Vs[buf][(db * 32 + li5) * 64
                                                     + ((tt * 2 + l5) ^ li7) * 8];
                const int jf = tt >> 1, m2 = tt & 1;
                u32x4 tw = {pw[jf][m2 * 4 + 0], pw[jf][m2 * 4 + 1],
                            pw[jf][m2 * 4 + 2], pw[jf][m2 * 4 + 3]};
                acc[db] = __builtin_amdgcn_mfma_f32_32x32x16_bf16(
                    vf, __builtin_bit_cast(bf16x8, tw), acc[db], 0, 0, 0);
            }
        __builtin_amdgcn_s_setprio(0);
        __syncthreads();
    }

    float l2 = lr + __shfl_xor(lr, 32);
    const float inv = 1.f / l2;
    // acc layout: D[row=d][col=q]: d = db*32 + (reg&3) + 8*(reg>>2) + 4*l5
#pragma unroll
    for (int db = 0; db < 2; ++db)
#pragma unroll
        for (int g = 0; g < 4; ++g) {
            ushort4 o;
            o.x = f2bf(acc[db][g * 4 + 0] * inv);
            o.y = f2bf(acc[db][g * 4 + 1] * inv);
            o.z = f2bf(acc[db][g * 4 + 2] * inv);
            o.w = f2bf(acc[db][g * 4 + 3] * inv);
            *(ushort4*)&AO[(size_t)(b * 2048 + qrow) * 1024 + h * 64
                           + db * 32 + g * 8 + l5 * 4] = o;
        }
}

// ---------------- launch ----------------
extern "C" void kernel_launch(void* const* d_in, const int* in_sizes, int n_in,
                              void* d_out, int out_size, void* d_ws, size_t ws_size,
                              hipStream_t stream) {
    const float* x   = (const float*)d_in[0];
    const float* Wq  = (const float*)d_in[2];
    const float* bq  = (const float*)d_in[3];
    const float* Wk  = (const float*)d_in[4];
    const float* bk  = (const float*)d_in[5];
    const float* Wv  = (const float*)d_in[6];
    const float* bv  = (const float*)d_in[7];
    const float* Wo  = (const float*)d_in[8];
    const float* bo  = (const float*)d_in[9];
    const float* ocr = (const float*)d_in[10];
    float* out = (float*)d_out;

    char* ws = (char*)d_ws;
    const size_t MB = 1024 * 1024;
    unsigned short* xb  = (unsigned short*)(ws);            // 16 MB (reused as AO)
    unsigned short* Wqb = (unsigned short*)(ws + 16 * MB);  // 2 MB each
    unsigned short* Wkb = (unsigned short*)(ws + 18 * MB);
    unsigned short* Wvb = (unsigned short*)(ws + 20 * MB);
    unsigned short* Wob = (unsigned short*)(ws + 22 * MB);
    unsigned short* Qb  = (unsigned short*)(ws + 24 * MB);  // 16 MB
    unsigned short* Kb  = (unsigned short*)(ws + 40 * MB);  // 16 MB
    unsigned short* VTb = (unsigned short*)(ws + 56 * MB);  // 16 MB, [bh][d][s]
    unsigned short* AO  = xb;  // x dead after projections

    cast_kernel<<<2048, 256, 0, stream>>>(x,  xb,  8388608 / 4);
    cast_kernel<<<512,  256, 0, stream>>>(Wq, Wqb, 1048576 / 4);
    cast_kernel<<<512,  256, 0, stream>>>(Wk, Wkb, 1048576 / 4);
    cast_kernel<<<512,  256, 0, stream>>>(Wv, Wvb, 1048576 / 4);
    cast_kernel<<<512,  256, 0, stream>>>(Wo, Wob, 1048576 / 4);

    dim3 g(8, 64);
    const float QSC = 0.125f * L2E;  // fold 1/sqrt(64) and log2(e) into Q
    gemm_bt<0><<<g, 256, 0, stream>>>(xb, Wqb, bq, ocr,     QSC, Qb,  nullptr);
    gemm_bt<0><<<g, 256, 0, stream>>>(xb, Wkb, bk, nullptr, 1.f, Kb,  nullptr);
    gemm_bt<2><<<g, 256, 0, stream>>>(xb, Wvb, bv, nullptr, 1.f, VTb, nullptr);

    attn_kernel<<<dim3(16, 64), 256, 0, stream>>>(Qb, Kb, VTb, AO);

    gemm_bt<1><<<g, 256, 0, stream>>>(AO, Wob, bo, nullptr, 1.f, nullptr, out);
}

// Round 5
// 197.571 us; speedup vs baseline: 1.2746x; 1.1632x over previous
//
#include <hip/hip_runtime.h>
#include <hip/hip_bf16.h>
#include <stdint.h>

typedef __attribute__((ext_vector_type(8))) short bf16x8;
typedef __attribute__((ext_vector_type(4))) float f32x4;
typedef __attribute__((ext_vector_type(16))) float f32x16;
typedef __attribute__((ext_vector_type(4))) unsigned u32x4;

#define L2E 1.4426950408889634f

static __device__ __forceinline__ unsigned short f2bf(float f) {
    __hip_bfloat16 h = __float2bfloat16(f);
    return __builtin_bit_cast(unsigned short, h);
}

static __device__ __forceinline__ void gl2lds16(const void* g, void* l) {
    __builtin_amdgcn_global_load_lds(
        (const __attribute__((address_space(1))) void*)g,
        (__attribute__((address_space(3))) void*)l,
        16, 0, 0);
}

// ---------------- cast fp32 -> bf16 ----------------
__global__ void cast_kernel(const float* __restrict__ src,
                            unsigned short* __restrict__ dst, int n4) {
    int i = blockIdx.x * blockDim.x + threadIdx.x;
    int stride = gridDim.x * blockDim.x;
    for (; i < n4; i += stride) {
        float4 v = ((const float4*)src)[i];
        ushort4 o;
        o.x = f2bf(v.x); o.y = f2bf(v.y); o.z = f2bf(v.z); o.w = f2bf(v.w);
        ((ushort4*)dst)[i] = o;
    }
}

// 4 weight matrices (1M elems each) in one dispatch; grid (256, 4)
__global__ void cast4_kernel(const float* __restrict__ s0, const float* __restrict__ s1,
                             const float* __restrict__ s2, const float* __restrict__ s3,
                             unsigned short* __restrict__ d0, unsigned short* __restrict__ d1,
                             unsigned short* __restrict__ d2, unsigned short* __restrict__ d3) {
    const int m = blockIdx.y;
    const float* src = m == 0 ? s0 : m == 1 ? s1 : m == 2 ? s2 : s3;
    unsigned short* dst = m == 0 ? d0 : m == 1 ? d1 : m == 2 ? d2 : d3;
    int i = blockIdx.x * blockDim.x + threadIdx.x;
    for (; i < 262144; i += 256 * 256) {
        float4 v = ((const float4*)src)[i];
        ushort4 o;
        o.x = f2bf(v.x); o.y = f2bf(v.y); o.z = f2bf(v.z); o.w = f2bf(v.w);
        ((ushort4*)dst)[i] = o;
    }
}

// ---------------- fused QKV projection GEMM ----------------
// C[i][j] = sum_k A[i][k] * W[j][k]; grid (24, 64) = 1536 blocks.
// nb 0-7 -> Q (scale + ocr bias, row-major), 8-15 -> K (row-major),
// 16-23 -> V (transposed store [bh][d][s]).
__global__ __launch_bounds__(256) void qkv_gemm(
    const unsigned short* __restrict__ A,
    const unsigned short* __restrict__ Wq,
    const unsigned short* __restrict__ Wk,
    const unsigned short* __restrict__ Wv,
    const float* __restrict__ bq,
    const float* __restrict__ bk,
    const float* __restrict__ bv,
    const float* __restrict__ ocr,
    float qscale,
    unsigned short* __restrict__ Qo,
    unsigned short* __restrict__ Ko,
    unsigned short* __restrict__ VTo)
{
    constexpr int K = 1024;
    __shared__ unsigned short As[128][64];
    __shared__ unsigned short Bs[128][64];

    const int tid  = threadIdx.x;
    const int wave = tid >> 6, lane = tid & 63;
    const int li = lane & 15, lg = lane >> 4;

    const int lin = blockIdx.y * 24 + blockIdx.x;
    const int n2  = (lin & 7) * 192 + (lin >> 3);   // XCD-chunked, bijective (1536%8==0)
    const int mb = n2 / 24, nbb = n2 - mb * 24;
    const int proj = nbb >> 3;
    const int m0 = mb * 128, n0 = (nbb & 7) * 128;

    const unsigned short* W = proj == 0 ? Wq : proj == 1 ? Wk : Wv;
    const float* bias = proj == 0 ? bq : proj == 1 ? bk : bv;

    const int wm = (wave >> 1) * 64, wn = (wave & 1) * 64;
    const int srow = wave * 8 + (lane >> 3);
    const int scol = (lane & 7) * 8;

    f32x4 acc[4][4] = {};

    for (int k0 = 0; k0 < K; k0 += 64) {
#pragma unroll
        for (int rnd = 0; rnd < 4; ++rnd)
            gl2lds16(A + (size_t)(m0 + rnd * 32 + srow) * K + k0 + scol,
                     &As[rnd * 32 + wave * 8][0]);
#pragma unroll
        for (int rnd = 0; rnd < 4; ++rnd)
            gl2lds16(W + (size_t)(n0 + rnd * 32 + srow) * K + k0 + scol,
                     &Bs[rnd * 32 + wave * 8][0]);
        __syncthreads();
#pragma unroll
        for (int kk = 0; kk < 64; kk += 32) {
            bf16x8 af[4], bfr[4];
#pragma unroll
            for (int m = 0; m < 4; ++m)
                af[m] = *(const bf16x8*)&As[wm + m * 16 + li][kk + lg * 8];
#pragma unroll
            for (int n = 0; n < 4; ++n)
                bfr[n] = *(const bf16x8*)&Bs[wn + n * 16 + li][kk + lg * 8];
#pragma unroll
            for (int m = 0; m < 4; ++m)
#pragma unroll
                for (int n = 0; n < 4; ++n)
                    acc[m][n] = __builtin_amdgcn_mfma_f32_16x16x32_bf16(
                        af[m], bfr[n], acc[m][n], 0, 0, 0);
        }
        __syncthreads();
    }

    const float scale = proj == 0 ? qscale : 1.f;
#pragma unroll
    for (int n = 0; n < 4; ++n) {
        const int col = n0 + wn + n * 16 + li;
        float bb = bias[col];
        if (proj == 0) bb += ocr[col];
#pragma unroll
        for (int m = 0; m < 4; ++m) {
            if (proj == 2) {
                const int row0 = m0 + wm + m * 16 + lg * 4;
                size_t addr = ((size_t)(((row0 >> 11) << 4) + (col >> 6)) * 64 + (col & 63)) * 2048
                              + (row0 & 2047);
                ushort4 o;
                o.x = f2bf(acc[m][n][0] + bb);
                o.y = f2bf(acc[m][n][1] + bb);
                o.z = f2bf(acc[m][n][2] + bb);
                o.w = f2bf(acc[m][n][3] + bb);
                *(ushort4*)&VTo[addr] = o;
            } else {
                unsigned short* dst = proj == 0 ? Qo : Ko;
#pragma unroll
                for (int r = 0; r < 4; ++r) {
                    const int row = m0 + wm + m * 16 + lg * 4 + r;
                    dst[(size_t)row * 1024 + col] = f2bf((acc[m][n][r] + bb) * scale);
                }
            }
        }
    }
}

// ---------------- output projection GEMM (f32 out) ----------------
__global__ __launch_bounds__(256) void out_gemm(
    const unsigned short* __restrict__ A,
    const unsigned short* __restrict__ W,
    const float* __restrict__ bias,
    float* __restrict__ of)
{
    constexpr int K = 1024;
    __shared__ unsigned short As[128][64];
    __shared__ unsigned short Bs[128][64];

    const int tid  = threadIdx.x;
    const int wave = tid >> 6, lane = tid & 63;
    const int li = lane & 15, lg = lane >> 4;
    const int lin = blockIdx.y * 8 + blockIdx.x;
    const int n2  = (lin & 7) * 64 + (lin >> 3);
    const int m0 = (n2 >> 3) * 128, n0 = (n2 & 7) * 128;
    const int wm = (wave >> 1) * 64, wn = (wave & 1) * 64;

    const int srow = wave * 8 + (lane >> 3);
    const int scol = (lane & 7) * 8;

    f32x4 acc[4][4] = {};

    for (int k0 = 0; k0 < K; k0 += 64) {
#pragma unroll
        for (int rnd = 0; rnd < 4; ++rnd)
            gl2lds16(A + (size_t)(m0 + rnd * 32 + srow) * K + k0 + scol,
                     &As[rnd * 32 + wave * 8][0]);
#pragma unroll
        for (int rnd = 0; rnd < 4; ++rnd)
            gl2lds16(W + (size_t)(n0 + rnd * 32 + srow) * K + k0 + scol,
                     &Bs[rnd * 32 + wave * 8][0]);
        __syncthreads();
#pragma unroll
        for (int kk = 0; kk < 64; kk += 32) {
            bf16x8 af[4], bfr[4];
#pragma unroll
            for (int m = 0; m < 4; ++m)
                af[m] = *(const bf16x8*)&As[wm + m * 16 + li][kk + lg * 8];
#pragma unroll
            for (int n = 0; n < 4; ++n)
                bfr[n] = *(const bf16x8*)&Bs[wn + n * 16 + li][kk + lg * 8];
#pragma unroll
            for (int m = 0; m < 4; ++m)
#pragma unroll
                for (int n = 0; n < 4; ++n)
                    acc[m][n] = __builtin_amdgcn_mfma_f32_16x16x32_bf16(
                        af[m], bfr[n], acc[m][n], 0, 0, 0);
        }
        __syncthreads();
    }

#pragma unroll
    for (int n = 0; n < 4; ++n) {
        const int col = n0 + wn + n * 16 + li;
        const float bb = bias[col];
#pragma unroll
        for (int m = 0; m < 4; ++m)
#pragma unroll
            for (int r = 0; r < 4; ++r) {
                const int row = m0 + wm + m * 16 + lg * 4 + r;
                of[(size_t)row * 1024 + col] = acc[m][n][r] + bb;
            }
    }
}

// ---------------- fused flash attention (32x32x16 MFMA) ----------------
// Q pre-scaled by (1/8)*log2(e). No max-subtraction. 4 waves x 32 q-rows.
// P -> PV-B-operand permutation = 8 x v_permlane32_swap_b32 per tile.
// Pack via v_cvt_pk_bf16_f32 (T12).
__global__ __launch_bounds__(256, 4) void attn_kernel(
    const unsigned short* __restrict__ Q,
    const unsigned short* __restrict__ Km,
    const unsigned short* __restrict__ VT,
    unsigned short* __restrict__ AO)
{
    __shared__ unsigned short Ks[2][4096];      // [buf][64 j][64 d] 16B-chunk XOR-swz
    __shared__ unsigned short Vs[2][4096];      // [buf][64 d][64 j] 16B-chunk XOR-swz

    const int tid  = threadIdx.x;
    const int w = tid >> 6, lane = tid & 63;
    const int li5 = lane & 31, l5 = lane >> 5, li7 = li5 & 7;

    const int p  = blockIdx.y * 16 + blockIdx.x;
    const int q_ = (p & 7) * 128 + (p >> 3);
    const int bx = q_ & 15, bh = q_ >> 4;
    const int b = bh >> 4, h = bh & 15;
    const int qb = bx * 128 + w * 32;
    const int qrow = qb + li5;

    const int srow = w * 16 + (lane >> 3);
    const int swz  = ((lane & 7) ^ (lane >> 3)) * 8;

    const unsigned short* Kg0 = Km + (size_t)(b * 2048 + srow) * 1024 + h * 64 + swz;
    const unsigned short* Vg0 = VT + ((size_t)bh * 64 + srow) * 2048 + swz;

    bf16x8 qf[4];
#pragma unroll
    for (int f = 0; f < 4; ++f)
        qf[f] = *(const bf16x8*)&Q[(size_t)(b * 2048 + qrow) * 1024 + h * 64
                                   + f * 16 + l5 * 8];

    f32x16 acc[2] = {};
    float ls0 = 0.f, ls1 = 0.f, ls2 = 0.f, ls3 = 0.f;

#pragma unroll
    for (int it = 0; it < 2; ++it) {
        gl2lds16(Kg0 + (size_t)(it * 8) * 1024, &Ks[0][(w * 2 + it) * 512]);
        gl2lds16(Vg0 + (size_t)(it * 8) * 2048, &Vs[0][(w * 2 + it) * 512]);
    }
    __syncthreads();

    for (int t = 0; t < 32; ++t) {
        const int buf = t & 1;
        const int j0 = t * 64;
        if (t < 31) {
            const int j1 = j0 + 64;
#pragma unroll
            for (int it = 0; it < 2; ++it) {
                gl2lds16(Kg0 + (size_t)(j1 + it * 8) * 1024, &Ks[buf ^ 1][(w * 2 + it) * 512]);
                gl2lds16(Vg0 + (size_t)(it * 8) * 2048 + j1, &Vs[buf ^ 1][(w * 2 + it) * 512]);
            }
        }

        // QK^T: st[jf][reg] = S[q=li5][j = j0 + jf*32 + (reg&3) + 8*(reg>>2) + 4*l5]
        f32x16 st[2];
        __builtin_amdgcn_s_setprio(1);
#pragma unroll
        for (int jf = 0; jf < 2; ++jf) {
            f32x16 z = {};
#pragma unroll
            for (int f = 0; f < 4; ++f) {
                bf16x8 kf = *(const bf16x8*)&Ks[buf][(jf * 32 + li5) * 64
                                                     + ((f * 2 + l5) ^ li7) * 8];
                z = __builtin_amdgcn_mfma_f32_32x32x16_bf16(kf, qf[f], z, 0, 0, 0);
            }
            st[jf] = z;
        }
        __builtin_amdgcn_s_setprio(0);

        if (j0 >= qb - 65 && j0 <= qb + 33) {
#pragma unroll
            for (int jf = 0; jf < 2; ++jf)
#pragma unroll
                for (int r = 0; r < 16; ++r) {
                    int j = j0 + jf * 32 + (r & 3) + 8 * (r >> 2) + 4 * l5;
                    int dq = qrow - j;
                    if ((unsigned)(dq + 2) <= 4u) st[jf][r] += 0.1f * L2E;
                }
        }

        // exp2 + cvt_pk pack: pw[jf][m] = bf16 pair (j even, j odd)
        unsigned pw[2][8];
#pragma unroll
        for (int jf = 0; jf < 2; ++jf) {
#pragma unroll
            for (int m = 0; m < 8; ++m) {
                float p0 = __builtin_amdgcn_exp2f(st[jf][2 * m]);
                float p1 = __builtin_amdgcn_exp2f(st[jf][2 * m + 1]);
                if (m == 0) { ls0 += p0; ls1 += p1; }
                else if (m == 1) { ls2 += p0; ls3 += p1; }
                else if (m == 2) { ls0 += p0; ls1 += p1; }
                else if (m == 3) { ls2 += p0; ls3 += p1; }
                else if (m == 4) { ls0 += p0; ls1 += p1; }
                else if (m == 5) { ls2 += p0; ls3 += p1; }
                else if (m == 6) { ls0 += p0; ls1 += p1; }
                else             { ls2 += p0; ls3 += p1; }
                asm("v_cvt_pk_bf16_f32 %0, %1, %2"
                    : "=v"(pw[jf][m]) : "v"(p0), "v"(p1));
            }
        }

        // single-transposition redistribution: 8 x permlane32_swap
#pragma unroll
        for (int jf = 0; jf < 2; ++jf)
#pragma unroll
            for (int m2 = 0; m2 < 2; ++m2)
#pragma unroll
                for (int m0_ = 0; m0_ < 2; ++m0_) {
                    unsigned a0 = pw[jf][m2 * 4 + m0_];
                    unsigned b0 = pw[jf][m2 * 4 + m0_ + 2];
                    asm volatile("v_permlane32_swap_b32 %0, %1"
                                 : "+v"(a0), "+v"(b0));
                    pw[jf][m2 * 4 + m0_]     = a0;
                    pw[jf][m2 * 4 + m0_ + 2] = b0;
                }

        // PV
        __builtin_amdgcn_s_setprio(1);
#pragma unroll
        for (int db = 0; db < 2; ++db)
#pragma unroll
            for (int tt = 0; tt < 4; ++tt) {
                bf16x8 vf = *(const bf16x8*)&Vs[buf][(db * 32 + li5) * 64
                                                     + ((tt * 2 + l5) ^ li7) * 8];
                const int jf = tt >> 1, m2 = tt & 1;
                u32x4 tw = {pw[jf][m2 * 4 + 0], pw[jf][m2 * 4 + 1],
                            pw[jf][m2 * 4 + 2], pw[jf][m2 * 4 + 3]};
                acc[db] = __builtin_amdgcn_mfma_f32_32x32x16_bf16(
                    vf, __builtin_bit_cast(bf16x8, tw), acc[db], 0, 0, 0);
            }
        __builtin_amdgcn_s_setprio(0);
        __syncthreads();
    }

    float lr = (ls0 + ls1) + (ls2 + ls3);
    float l2 = lr + __shfl_xor(lr, 32);
    const float inv = 1.f / l2;
#pragma unroll
    for (int db = 0; db < 2; ++db)
#pragma unroll
        for (int g = 0; g < 4; ++g) {
            ushort4 o;
            o.x = f2bf(acc[db][g * 4 + 0] * inv);
            o.y = f2bf(acc[db][g * 4 + 1] * inv);
            o.z = f2bf(acc[db][g * 4 + 2] * inv);
            o.w = f2bf(acc[db][g * 4 + 3] * inv);
            *(ushort4*)&AO[(size_t)(b * 2048 + qrow) * 1024 + h * 64
                           + db * 32 + g * 8 + l5 * 4] = o;
        }
}

// ---------------- launch ----------------
extern "C" void kernel_launch(void* const* d_in, const int* in_sizes, int n_in,
                              void* d_out, int out_size, void* d_ws, size_t ws_size,
                              hipStream_t stream) {
    const float* x   = (const float*)d_in[0];
    const float* Wq  = (const float*)d_in[2];
    const float* bq  = (const float*)d_in[3];
    const float* Wk  = (const float*)d_in[4];
    const float* bk  = (const float*)d_in[5];
    const float* Wv  = (const float*)d_in[6];
    const float* bv  = (const float*)d_in[7];
    const float* Wo  = (const float*)d_in[8];
    const float* bo  = (const float*)d_in[9];
    const float* ocr = (const float*)d_in[10];
    float* out = (float*)d_out;

    char* ws = (char*)d_ws;
    const size_t MB = 1024 * 1024;
    unsigned short* xb  = (unsigned short*)(ws);            // 16 MB (reused as AO)
    unsigned short* Wqb = (unsigned short*)(ws + 16 * MB);  // 2 MB each
    unsigned short* Wkb = (unsigned short*)(ws + 18 * MB);
    unsigned short* Wvb = (unsigned short*)(ws + 20 * MB);
    unsigned short* Wob = (unsigned short*)(ws + 22 * MB);
    unsigned short* Qb  = (unsigned short*)(ws + 24 * MB);  // 16 MB
    unsigned short* Kb  = (unsigned short*)(ws + 40 * MB);  // 16 MB
    unsigned short* VTb = (unsigned short*)(ws + 56 * MB);  // 16 MB, [bh][d][s]
    unsigned short* AO  = xb;  // x dead after projections

    cast_kernel<<<2048, 256, 0, stream>>>(x, xb, 8388608 / 4);
    cast4_kernel<<<dim3(256, 4), 256, 0, stream>>>(Wq, Wk, Wv, Wo,
                                                   Wqb, Wkb, Wvb, Wob);

    const float QSC = 0.125f * L2E;  // fold 1/sqrt(64) and log2(e) into Q
    qkv_gemm<<<dim3(24, 64), 256, 0, stream>>>(xb, Wqb, Wkb, Wvb,
                                               bq, bk, bv, ocr, QSC,
                                               Qb, Kb, VTb);

    attn_kernel<<<dim3(16, 64), 256, 0, stream>>>(Qb, Kb, VTb, AO);

    out_gemm<<<dim3(8, 64), 256, 0, stream>>>(AO, Wob, bo, out);
}

// Round 6
// 193.285 us; speedup vs baseline: 1.3028x; 1.0222x over previous
//
#include <hip/hip_runtime.h>
#include <hip/hip_bf16.h>
#include <stdint.h>

typedef __attribute__((ext_vector_type(8))) short bf16x8;
typedef __attribute__((ext_vector_type(4))) float f32x4;
typedef __attribute__((ext_vector_type(16))) float f32x16;
typedef __attribute__((ext_vector_type(4))) unsigned u32x4;

#define L2E 1.4426950408889634f

static __device__ __forceinline__ unsigned short f2bf(float f) {
    __hip_bfloat16 h = __float2bfloat16(f);
    return __builtin_bit_cast(unsigned short, h);
}

static __device__ __forceinline__ void gl2lds16(const void* g, void* l) {
    __builtin_amdgcn_global_load_lds(
        (const __attribute__((address_space(1))) void*)g,
        (__attribute__((address_space(3))) void*)l,
        16, 0, 0);
}

// ---------------- cast fp32 -> bf16 ----------------
__global__ void cast_kernel(const float* __restrict__ src,
                            unsigned short* __restrict__ dst, int n4) {
    int i = blockIdx.x * blockDim.x + threadIdx.x;
    int stride = gridDim.x * blockDim.x;
    for (; i < n4; i += stride) {
        float4 v = ((const float4*)src)[i];
        ushort4 o;
        o.x = f2bf(v.x); o.y = f2bf(v.y); o.z = f2bf(v.z); o.w = f2bf(v.w);
        ((ushort4*)dst)[i] = o;
    }
}

// 4 weight matrices (1M elems each) in one dispatch; grid (256, 4)
__global__ void cast4_kernel(const float* __restrict__ s0, const float* __restrict__ s1,
                             const float* __restrict__ s2, const float* __restrict__ s3,
                             unsigned short* __restrict__ d0, unsigned short* __restrict__ d1,
                             unsigned short* __restrict__ d2, unsigned short* __restrict__ d3) {
    const int m = blockIdx.y;
    const float* src = m == 0 ? s0 : m == 1 ? s1 : m == 2 ? s2 : s3;
    unsigned short* dst = m == 0 ? d0 : m == 1 ? d1 : m == 2 ? d2 : d3;
    int i = blockIdx.x * blockDim.x + threadIdx.x;
    for (; i < 262144; i += 256 * 256) {
        float4 v = ((const float4*)src)[i];
        ushort4 o;
        o.x = f2bf(v.x); o.y = f2bf(v.y); o.z = f2bf(v.z); o.w = f2bf(v.w);
        ((ushort4*)dst)[i] = o;
    }
}

// ---------------- fused QKV projection GEMM ----------------
// C[i][j] = sum_k A[i][k] * W[j][k]; grid (24, 64) = 1536 blocks.
// nb 0-7 -> Q (scale + ocr bias, row-major), 8-15 -> K (row-major),
// 16-23 -> V (transposed store [bh][d][s]).
__global__ __launch_bounds__(256) void qkv_gemm(
    const unsigned short* __restrict__ A,
    const unsigned short* __restrict__ Wq,
    const unsigned short* __restrict__ Wk,
    const unsigned short* __restrict__ Wv,
    const float* __restrict__ bq,
    const float* __restrict__ bk,
    const float* __restrict__ bv,
    const float* __restrict__ ocr,
    float qscale,
    unsigned short* __restrict__ Qo,
    unsigned short* __restrict__ Ko,
    unsigned short* __restrict__ VTo)
{
    constexpr int K = 1024;
    __shared__ unsigned short As[128][64];
    __shared__ unsigned short Bs[128][64];

    const int tid  = threadIdx.x;
    const int wave = tid >> 6, lane = tid & 63;
    const int li = lane & 15, lg = lane >> 4;

    const int lin = blockIdx.y * 24 + blockIdx.x;
    const int n2  = (lin & 7) * 192 + (lin >> 3);   // XCD-chunked, bijective (1536%8==0)
    const int mb = n2 / 24, nbb = n2 - mb * 24;
    const int proj = nbb >> 3;
    const int m0 = mb * 128, n0 = (nbb & 7) * 128;

    const unsigned short* W = proj == 0 ? Wq : proj == 1 ? Wk : Wv;
    const float* bias = proj == 0 ? bq : proj == 1 ? bk : bv;

    const int wm = (wave >> 1) * 64, wn = (wave & 1) * 64;
    const int srow = wave * 8 + (lane >> 3);
    const int scol = (lane & 7) * 8;

    f32x4 acc[4][4] = {};

    for (int k0 = 0; k0 < K; k0 += 64) {
#pragma unroll
        for (int rnd = 0; rnd < 4; ++rnd)
            gl2lds16(A + (size_t)(m0 + rnd * 32 + srow) * K + k0 + scol,
                     &As[rnd * 32 + wave * 8][0]);
#pragma unroll
        for (int rnd = 0; rnd < 4; ++rnd)
            gl2lds16(W + (size_t)(n0 + rnd * 32 + srow) * K + k0 + scol,
                     &Bs[rnd * 32 + wave * 8][0]);
        __syncthreads();
#pragma unroll
        for (int kk = 0; kk < 64; kk += 32) {
            bf16x8 af[4], bfr[4];
#pragma unroll
            for (int m = 0; m < 4; ++m)
                af[m] = *(const bf16x8*)&As[wm + m * 16 + li][kk + lg * 8];
#pragma unroll
            for (int n = 0; n < 4; ++n)
                bfr[n] = *(const bf16x8*)&Bs[wn + n * 16 + li][kk + lg * 8];
#pragma unroll
            for (int m = 0; m < 4; ++m)
#pragma unroll
                for (int n = 0; n < 4; ++n)
                    acc[m][n] = __builtin_amdgcn_mfma_f32_16x16x32_bf16(
                        af[m], bfr[n], acc[m][n], 0, 0, 0);
        }
        __syncthreads();
    }

    const float scale = proj == 0 ? qscale : 1.f;
#pragma unroll
    for (int n = 0; n < 4; ++n) {
        const int col = n0 + wn + n * 16 + li;
        float bb = bias[col];
        if (proj == 0) bb += ocr[col];
#pragma unroll
        for (int m = 0; m < 4; ++m) {
            if (proj == 2) {
                const int row0 = m0 + wm + m * 16 + lg * 4;
                size_t addr = ((size_t)(((row0 >> 11) << 4) + (col >> 6)) * 64 + (col & 63)) * 2048
                              + (row0 & 2047);
                ushort4 o;
                o.x = f2bf(acc[m][n][0] + bb);
                o.y = f2bf(acc[m][n][1] + bb);
                o.z = f2bf(acc[m][n][2] + bb);
                o.w = f2bf(acc[m][n][3] + bb);
                *(ushort4*)&VTo[addr] = o;
            } else {
                unsigned short* dst = proj == 0 ? Qo : Ko;
#pragma unroll
                for (int r = 0; r < 4; ++r) {
                    const int row = m0 + wm + m * 16 + lg * 4 + r;
                    dst[(size_t)row * 1024 + col] = f2bf((acc[m][n][r] + bb) * scale);
                }
            }
        }
    }
}

// ---------------- output projection GEMM (f32 out) ----------------
__global__ __launch_bounds__(256) void out_gemm(
    const unsigned short* __restrict__ A,
    const unsigned short* __restrict__ W,
    const float* __restrict__ bias,
    float* __restrict__ of)
{
    constexpr int K = 1024;
    __shared__ unsigned short As[128][64];
    __shared__ unsigned short Bs[128][64];

    const int tid  = threadIdx.x;
    const int wave = tid >> 6, lane = tid & 63;
    const int li = lane & 15, lg = lane >> 4;
    const int lin = blockIdx.y * 8 + blockIdx.x;
    const int n2  = (lin & 7) * 64 + (lin >> 3);
    const int m0 = (n2 >> 3) * 128, n0 = (n2 & 7) * 128;
    const int wm = (wave >> 1) * 64, wn = (wave & 1) * 64;

    const int srow = wave * 8 + (lane >> 3);
    const int scol = (lane & 7) * 8;

    f32x4 acc[4][4] = {};

    for (int k0 = 0; k0 < K; k0 += 64) {
#pragma unroll
        for (int rnd = 0; rnd < 4; ++rnd)
            gl2lds16(A + (size_t)(m0 + rnd * 32 + srow) * K + k0 + scol,
                     &As[rnd * 32 + wave * 8][0]);
#pragma unroll
        for (int rnd = 0; rnd < 4; ++rnd)
            gl2lds16(W + (size_t)(n0 + rnd * 32 + srow) * K + k0 + scol,
                     &Bs[rnd * 32 + wave * 8][0]);
        __syncthreads();
#pragma unroll
        for (int kk = 0; kk < 64; kk += 32) {
            bf16x8 af[4], bfr[4];
#pragma unroll
            for (int m = 0; m < 4; ++m)
                af[m] = *(const bf16x8*)&As[wm + m * 16 + li][kk + lg * 8];
#pragma unroll
            for (int n = 0; n < 4; ++n)
                bfr[n] = *(const bf16x8*)&Bs[wn + n * 16 + li][kk + lg * 8];
#pragma unroll
            for (int m = 0; m < 4; ++m)
#pragma unroll
                for (int n = 0; n < 4; ++n)
                    acc[m][n] = __builtin_amdgcn_mfma_f32_16x16x32_bf16(
                        af[m], bfr[n], acc[m][n], 0, 0, 0);
        }
        __syncthreads();
    }

#pragma unroll
    for (int n = 0; n < 4; ++n) {
        const int col = n0 + wn + n * 16 + li;
        const float bb = bias[col];
#pragma unroll
        for (int m = 0; m < 4; ++m)
#pragma unroll
            for (int r = 0; r < 4; ++r) {
                const int row = m0 + wm + m * 16 + lg * 4 + r;
                of[(size_t)row * 1024 + col] = acc[m][n][r] + bb;
            }
    }
}

// ---------------- fused flash attention (32x32x16 MFMA, 2 q-sets/wave) -----
// Q pre-scaled by (1/8)*log2(e). No max-subtraction. 4 waves x 64 q-rows
// (2 sets of 32). K/V frag reads amortized over both sets (halves LDS traffic).
// P -> PV-B-operand permutation = 8 x v_permlane32_swap_b32 per set per tile.
__global__ __launch_bounds__(256, 2) void attn_kernel(
    const unsigned short* __restrict__ Q,
    const unsigned short* __restrict__ Km,
    const unsigned short* __restrict__ VT,
    unsigned short* __restrict__ AO)
{
    __shared__ unsigned short Ks[2][4096];      // [buf][64 j][64 d] 16B-chunk XOR-swz
    __shared__ unsigned short Vs[2][4096];      // [buf][64 d][64 j] 16B-chunk XOR-swz

    const int tid  = threadIdx.x;
    const int w = tid >> 6, lane = tid & 63;
    const int li5 = lane & 31, l5 = lane >> 5, li7 = li5 & 7;

    // bijective XCD-chunked remap over 512 blocks (8 x 64 grid)
    const int p  = blockIdx.y * 8 + blockIdx.x;
    const int q_ = (p & 7) * 64 + (p >> 3);
    const int bx = q_ & 7, bh = q_ >> 3;
    const int b = bh >> 4, h = bh & 15;
    const int qb = bx * 256 + w * 64;           // this wave's 64 q-rows

    const int srow = w * 16 + (lane >> 3);
    const int swz  = ((lane & 7) ^ (lane >> 3)) * 8;

    const unsigned short* Kg0 = Km + (size_t)(b * 2048 + srow) * 1024 + h * 64 + swz;
    const unsigned short* Vg0 = VT + ((size_t)bh * 64 + srow) * 2048 + swz;

    // Q B-fragments per set: qf[s][f] = Q[qb + s*32 + li5][d = f*16 + l5*8 + e]
    bf16x8 qf[2][4];
#pragma unroll
    for (int s = 0; s < 2; ++s)
#pragma unroll
        for (int f = 0; f < 4; ++f)
            qf[s][f] = *(const bf16x8*)&Q[(size_t)(b * 2048 + qb + s * 32 + li5) * 1024
                                          + h * 64 + f * 16 + l5 * 8];

    f32x16 acc[2][2] = {};
    float ls00 = 0.f, ls01 = 0.f, ls10 = 0.f, ls11 = 0.f;

#pragma unroll
    for (int it = 0; it < 2; ++it) {
        gl2lds16(Kg0 + (size_t)(it * 8) * 1024, &Ks[0][(w * 2 + it) * 512]);
        gl2lds16(Vg0 + (size_t)(it * 8) * 2048, &Vs[0][(w * 2 + it) * 512]);
    }
    __syncthreads();

    for (int t = 0; t < 32; ++t) {
        const int buf = t & 1;
        const int j0 = t * 64;
        if (t < 31) {
            const int j1 = j0 + 64;
#pragma unroll
            for (int it = 0; it < 2; ++it) {
                gl2lds16(Kg0 + (size_t)(j1 + it * 8) * 1024, &Ks[buf ^ 1][(w * 2 + it) * 512]);
                gl2lds16(Vg0 + (size_t)(it * 8) * 2048 + j1, &Vs[buf ^ 1][(w * 2 + it) * 512]);
            }
        }

        // K fragments, shared by both q-sets
        bf16x8 kf[2][4];
#pragma unroll
        for (int jf = 0; jf < 2; ++jf)
#pragma unroll
            for (int f = 0; f < 4; ++f)
                kf[jf][f] = *(const bf16x8*)&Ks[buf][(jf * 32 + li5) * 64
                                                     + ((f * 2 + l5) ^ li7) * 8];

        unsigned pw[2][2][8];
#pragma unroll
        for (int s = 0; s < 2; ++s) {
            // QK^T: st[jf][reg] = S[q][j = j0 + jf*32 + (reg&3) + 8*(reg>>2) + 4*l5]
            f32x16 st[2];
            __builtin_amdgcn_s_setprio(1);
#pragma unroll
            for (int jf = 0; jf < 2; ++jf) {
                f32x16 z = {};
#pragma unroll
                for (int f = 0; f < 4; ++f)
                    z = __builtin_amdgcn_mfma_f32_32x32x16_bf16(kf[jf][f], qf[s][f], z, 0, 0, 0);
                st[jf] = z;
            }
            __builtin_amdgcn_s_setprio(0);

            const int qbs = qb + s * 32;
            if (j0 >= qbs - 65 && j0 <= qbs + 33) {
#pragma unroll
                for (int jf = 0; jf < 2; ++jf)
#pragma unroll
                    for (int r = 0; r < 16; ++r) {
                        int j = j0 + jf * 32 + (r & 3) + 8 * (r >> 2) + 4 * l5;
                        int dq = (qbs + li5) - j;
                        if ((unsigned)(dq + 2) <= 4u) st[jf][r] += 0.1f * L2E;
                    }
            }

            // exp2 + cvt_pk pack
#pragma unroll
            for (int jf = 0; jf < 2; ++jf)
#pragma unroll
                for (int m = 0; m < 8; ++m) {
                    float p0 = __builtin_amdgcn_exp2f(st[jf][2 * m]);
                    float p1 = __builtin_amdgcn_exp2f(st[jf][2 * m + 1]);
                    float pp = p0 + p1;
                    if (s == 0) { if (m & 1) ls01 += pp; else ls00 += pp; }
                    else        { if (m & 1) ls11 += pp; else ls10 += pp; }
                    asm("v_cvt_pk_bf16_f32 %0, %1, %2"
                        : "=v"(pw[s][jf][m]) : "v"(p0), "v"(p1));
                }

            // single-transposition redistribution: 8 x permlane32_swap
#pragma unroll
            for (int jf = 0; jf < 2; ++jf)
#pragma unroll
                for (int m2 = 0; m2 < 2; ++m2)
#pragma unroll
                    for (int m0_ = 0; m0_ < 2; ++m0_) {
                        unsigned a0 = pw[s][jf][m2 * 4 + m0_];
                        unsigned b0 = pw[s][jf][m2 * 4 + m0_ + 2];
                        asm volatile("v_permlane32_swap_b32 %0, %1"
                                     : "+v"(a0), "+v"(b0));
                        pw[s][jf][m2 * 4 + m0_]     = a0;
                        pw[s][jf][m2 * 4 + m0_ + 2] = b0;
                    }
        }

        // PV: V fragments shared by both sets
        __builtin_amdgcn_s_setprio(1);
#pragma unroll
        for (int db = 0; db < 2; ++db)
#pragma unroll
            for (int tt = 0; tt < 4; ++tt) {
                bf16x8 vf = *(const bf16x8*)&Vs[buf][(db * 32 + li5) * 64
                                                     + ((tt * 2 + l5) ^ li7) * 8];
                const int jf = tt >> 1, m2 = tt & 1;
#pragma unroll
                for (int s = 0; s < 2; ++s) {
                    u32x4 tw = {pw[s][jf][m2 * 4 + 0], pw[s][jf][m2 * 4 + 1],
                                pw[s][jf][m2 * 4 + 2], pw[s][jf][m2 * 4 + 3]};
                    acc[s][db] = __builtin_amdgcn_mfma_f32_32x32x16_bf16(
                        vf, __builtin_bit_cast(bf16x8, tw), acc[s][db], 0, 0, 0);
                }
            }
        __builtin_amdgcn_s_setprio(0);
        __syncthreads();
    }

#pragma unroll
    for (int s = 0; s < 2; ++s) {
        float lr = s == 0 ? (ls00 + ls01) : (ls10 + ls11);
        float l2 = lr + __shfl_xor(lr, 32);
        const float inv = 1.f / l2;
        const int qrow = qb + s * 32 + li5;
#pragma unroll
        for (int db = 0; db < 2; ++db)
#pragma unroll
            for (int g = 0; g < 4; ++g) {
                ushort4 o;
                o.x = f2bf(acc[s][db][g * 4 + 0] * inv);
                o.y = f2bf(acc[s][db][g * 4 + 1] * inv);
                o.z = f2bf(acc[s][db][g * 4 + 2] * inv);
                o.w = f2bf(acc[s][db][g * 4 + 3] * inv);
                *(ushort4*)&AO[(size_t)(b * 2048 + qrow) * 1024 + h * 64
                               + db * 32 + g * 8 + l5 * 4] = o;
            }
    }
}

// ---------------- launch ----------------
extern "C" void kernel_launch(void* const* d_in, const int* in_sizes, int n_in,
                              void* d_out, int out_size, void* d_ws, size_t ws_size,
                              hipStream_t stream) {
    const float* x   = (const float*)d_in[0];
    const float* Wq  = (const float*)d_in[2];
    const float* bq  = (const float*)d_in[3];
    const float* Wk  = (const float*)d_in[4];
    const float* bk  = (const float*)d_in[5];
    const float* Wv  = (const float*)d_in[6];
    const float* bv  = (const float*)d_in[7];
    const float* Wo  = (const float*)d_in[8];
    const float* bo  = (const float*)d_in[9];
    const float* ocr = (const float*)d_in[10];
    float* out = (float*)d_out;

    char* ws = (char*)d_ws;
    const size_t MB = 1024 * 1024;
    unsigned short* xb  = (unsigned short*)(ws);            // 16 MB (reused as AO)
    unsigned short* Wqb = (unsigned short*)(ws + 16 * MB);  // 2 MB each
    unsigned short* Wkb = (unsigned short*)(ws + 18 * MB);
    unsigned short* Wvb = (unsigned short*)(ws + 20 * MB);
    unsigned short* Wob = (unsigned short*)(ws + 22 * MB);
    unsigned short* Qb  = (unsigned short*)(ws + 24 * MB);  // 16 MB
    unsigned short* Kb  = (unsigned short*)(ws + 40 * MB);  // 16 MB
    unsigned short* VTb = (unsigned short*)(ws + 56 * MB);  // 16 MB, [bh][d][s]
    unsigned short* AO  = xb;  // x dead after projections

    cast_kernel<<<2048, 256, 0, stream>>>(x, xb, 8388608 / 4);
    cast4_kernel<<<dim3(256, 4), 256, 0, stream>>>(Wq, Wk, Wv, Wo,
                                                   Wqb, Wkb, Wvb, Wob);

    const float QSC = 0.125f * L2E;  // fold 1/sqrt(64) and log2(e) into Q
    qkv_gemm<<<dim3(24, 64), 256, 0, stream>>>(xb, Wqb, Wkb, Wvb,
                                               bq, bk, bv, ocr, QSC,
                                               Qb, Kb, VTb);

    attn_kernel<<<dim3(8, 64), 256, 0, stream>>>(Qb, Kb, VTb, AO);

    out_gemm<<<dim3(8, 64), 256, 0, stream>>>(AO, Wob, bo, out);
}